// Round 1
// baseline (2572.486 us; speedup 1.0000x reference)
//
#include <hip/hip_runtime.h>
#include <hip/hip_bf16.h>
#include <math.h>

#define N_NODES 50000
#define E_EDGES 800000
#define ET (E_EDGES + N_NODES)
#define NFEAT 16
#define EFEAT 8
#define HID 32
#define HEADS 4
#define HC 128

// ---- order-preserving float<->uint encoding for atomicMax on floats ----
__device__ __forceinline__ unsigned fenc(float f) {
    unsigned u = __float_as_uint(f);
    return (u & 0x80000000u) ? ~u : (u | 0x80000000u);
}
__device__ __forceinline__ float fdec(unsigned u) {
    return __uint_as_float((u & 0x80000000u) ? (u & 0x7FFFFFFFu) : ~u);
}
__device__ __forceinline__ float lrelu(float v) { return v > 0.f ? v : 0.2f * v; }

// ---- K1: h = x @ W ; alpha_src/dst = einsum(h, aS/aD) per head ----
// block = 256 threads; GROUPS = 256/HOUT groups of HOUT lanes; each group does NPT nodes.
template<int FIN, int HOUT, int H>
__global__ void k1_gemm_alpha(const float* __restrict__ x, const float* __restrict__ W,
                              const float* __restrict__ aS, const float* __restrict__ aD,
                              float* __restrict__ hout, float* __restrict__ asrc,
                              float* __restrict__ adst, int n_nodes)
{
    constexpr int GROUPS = 256 / HOUT;
    constexpr int NPT = 4;
    constexpr int NPB = GROUPS * NPT;
    __shared__ float xs[NPB * (FIN + 1)];
    const int tid = threadIdx.x;
    const int nb0 = blockIdx.x * NPB;
    for (int idx = tid; idx < NPB * FIN; idx += 256) {
        int node = idx / FIN, k = idx % FIN;
        int gn = nb0 + node;
        xs[node * (FIN + 1) + k] = (gn < n_nodes) ? x[gn * FIN + k] : 0.f;
    }
    __syncthreads();
    const int c = tid % HOUT;
    const int g = tid / HOUT;
    const int head = c / HID;
    const int cc = c % HID;
    const float aSv = aS[head * HID + cc];
    const float aDv = aD[head * HID + cc];
    float acc[NPT];
#pragma unroll
    for (int i = 0; i < NPT; i++) acc[i] = 0.f;
    for (int k = 0; k < FIN; k++) {
        float w = W[k * HOUT + c];
#pragma unroll
        for (int i = 0; i < NPT; i++)
            acc[i] += w * xs[(g * NPT + i) * (FIN + 1) + k];
    }
#pragma unroll
    for (int i = 0; i < NPT; i++) {
        int n = nb0 + g * NPT + i;
        bool ok = (n < n_nodes);
        float h = acc[i];
        if (ok) hout[n * HOUT + c] = h;
        float pa = h * aSv, pb = h * aDv;
#pragma unroll
        for (int off = 16; off >= 1; off >>= 1) {
            pa += __shfl_xor(pa, off, 32);
            pb += __shfl_xor(pb, off, 32);
        }
        if (ok && cc == 0) { asrc[n * H + head] = pa; adst[n * H + head] = pb; }
    }
}

// ---- K2: per-edge leaky_relu score, segment max into m[dst] (encoded) ----
template<int H>
__global__ void k2_edge_max(const int* __restrict__ ei0, const int* __restrict__ ei1,
                            const float* __restrict__ asrc, const float* __restrict__ adst,
                            unsigned* __restrict__ m)
{
    int e = blockIdx.x * blockDim.x + threadIdx.x;
    if (e >= ET) return;
    int s, d;
    if (e < E_EDGES) { s = ei0[e]; d = ei1[e]; } else { s = e - E_EDGES; d = s; }
#pragma unroll
    for (int h = 0; h < H; h++) {
        float v = lrelu(asrc[s * H + h] + adst[d * H + h]);
        atomicMax(&m[d * H + h], fenc(v));
    }
}

// ---- K3: ex = exp(e - m[dst]); acc[dst] += ex * h[src]; ssum[dst] += ex ----
template<int H, int C>
__global__ void k3_edge_aggr(const int* __restrict__ ei0, const int* __restrict__ ei1,
                             const float* __restrict__ asrc, const float* __restrict__ adst,
                             const unsigned* __restrict__ m, const float* __restrict__ hbuf,
                             float* __restrict__ acc, float* __restrict__ ssum)
{
    constexpr int TPE = H * C;
    constexpr int EPB = 256 / TPE;
    const int tid = threadIdx.x;
    int e = blockIdx.x * EPB + tid / TPE;
    if (e >= ET) return;
    const int t = tid % TPE;
    const int head = t / C;
    const int cc = t % C;
    int s, d;
    if (e < E_EDGES) { s = ei0[e]; d = ei1[e]; } else { s = e - E_EDGES; d = s; }
    float ev = lrelu(asrc[s * H + head] + adst[d * H + head]);
    float ex = __expf(ev - fdec(m[d * H + head]));
    float contrib = ex * hbuf[s * TPE + t];
    unsafeAtomicAdd(&acc[d * TPE + t], contrib);
    if (cc == 0) unsafeAtomicAdd(&ssum[d * H + head], ex);
}

// ---- K4: out = acc / (ssum + eps) + b ; optional ELU ; in place ----
template<int H, int C, bool DO_ELU>
__global__ void k4_norm(float* __restrict__ acc, const float* __restrict__ ssum,
                        const float* __restrict__ b)
{
    int idx = blockIdx.x * blockDim.x + threadIdx.x;
    if (idx >= N_NODES * H * C) return;
    int n = idx / (H * C);
    int t = idx % (H * C);
    int head = t / C;
    float v = acc[idx] / (ssum[n * H + head] + 1e-16f) + b[t];
    if (DO_ELU) v = v > 0.f ? v : __expf(v) - 1.f;
    acc[idx] = v;
}

// ---- K5: per-edge MLP 72 -> 32 -> 32 -> 1, softplus ----
__global__ void k5_mlp(const int* __restrict__ ei0, const int* __restrict__ ei1,
                       const float* __restrict__ h3, const float* __restrict__ ea,
                       const float* __restrict__ Wm1, const float* __restrict__ bm1,
                       const float* __restrict__ Wm2, const float* __restrict__ bm2,
                       const float* __restrict__ Wm3, const float* __restrict__ bm3,
                       float* __restrict__ out)
{
    __shared__ float w1[72 * 32], w2[32 * 32], w3[32], b1s[32], b2s[32];
    __shared__ float b3s;
    const int tid = threadIdx.x;
    for (int i = tid; i < 72 * 32; i += 256) w1[i] = Wm1[i];
    for (int i = tid; i < 32 * 32; i += 256) w2[i] = Wm2[i];
    if (tid < 32) { w3[tid] = Wm3[tid]; b1s[tid] = bm1[tid]; b2s[tid] = bm2[tid]; }
    if (tid == 0) b3s = bm3[0];
    __syncthreads();
    int e = blockIdx.x * 256 + tid;
    if (e >= E_EDGES) return;
    int s = ei0[e], d = ei1[e];
    float in[72];
#pragma unroll
    for (int k = 0; k < 32; k++) in[k] = h3[s * 32 + k];
#pragma unroll
    for (int k = 0; k < 32; k++) in[32 + k] = h3[d * 32 + k];
#pragma unroll
    for (int k = 0; k < 8; k++) in[64 + k] = ea[e * 8 + k];
    float z1[32];
#pragma unroll
    for (int j = 0; j < 32; j++) {
        float a = b1s[j];
#pragma unroll
        for (int k = 0; k < 72; k++) a += in[k] * w1[k * 32 + j];
        z1[j] = a > 0.f ? a : 0.f;
    }
    float z3 = b3s;
#pragma unroll
    for (int j = 0; j < 32; j++) {
        float a = b2s[j];
#pragma unroll
        for (int k = 0; k < 32; k++) a += z1[k] * w2[k * 32 + j];
        z3 += (a > 0.f ? a : 0.f) * w3[j];
    }
    out[e] = (z3 > 20.f) ? z3 : log1pf(__expf(z3));
}

extern "C" void kernel_launch(void* const* d_in, const int* in_sizes, int n_in,
                              void* d_out, int out_size, void* d_ws, size_t ws_size,
                              hipStream_t stream)
{
    const float* x   = (const float*)d_in[0];
    const int*   ei  = (const int*)d_in[1];
    const int*   ei0 = ei;
    const int*   ei1 = ei + E_EDGES;
    const float* ea  = (const float*)d_in[2];
    const float* W1  = (const float*)d_in[3];
    const float* aS1 = (const float*)d_in[4];
    const float* aD1 = (const float*)d_in[5];
    const float* b1  = (const float*)d_in[6];
    const float* W2  = (const float*)d_in[7];
    const float* aS2 = (const float*)d_in[8];
    const float* aD2 = (const float*)d_in[9];
    const float* b2  = (const float*)d_in[10];
    const float* W3  = (const float*)d_in[11];
    const float* aS3 = (const float*)d_in[12];
    const float* aD3 = (const float*)d_in[13];
    const float* b3  = (const float*)d_in[14];
    const float* Wm1 = (const float*)d_in[15];
    const float* bm1 = (const float*)d_in[16];
    const float* Wm2 = (const float*)d_in[17];
    const float* bm2 = (const float*)d_in[18];
    const float* Wm3 = (const float*)d_in[19];
    const float* bm3 = (const float*)d_in[20];

    float* ws = (float*)d_ws;
    float* bufA = ws;                                   // [N,128] h of current layer
    float* bufB = bufA + (size_t)N_NODES * HC;          // [N,128] acc / layer output
    float* asrc = bufB + (size_t)N_NODES * HC;          // [N,4]
    float* adst = asrc + (size_t)N_NODES * HEADS;       // [N,4]
    unsigned* menc = (unsigned*)(adst + (size_t)N_NODES * HEADS);  // [N,4]
    float* ssum = (float*)(menc + (size_t)N_NODES * HEADS);        // [N,4]

    float* out = (float*)d_out;

    // ---------------- Layer 1: x[N,16] -> bufB[N,128] (ELU) ----------------
    k1_gemm_alpha<NFEAT, HC, HEADS><<<(N_NODES + 7) / 8, 256, 0, stream>>>(
        x, W1, aS1, aD1, bufA, asrc, adst, N_NODES);
    hipMemsetAsync(bufB, 0, (size_t)N_NODES * HC * sizeof(float), stream);
    hipMemsetAsync(menc, 0, (size_t)N_NODES * HEADS * sizeof(unsigned), stream);
    hipMemsetAsync(ssum, 0, (size_t)N_NODES * HEADS * sizeof(float), stream);
    k2_edge_max<HEADS><<<(ET + 255) / 256, 256, 0, stream>>>(ei0, ei1, asrc, adst, menc);
    k3_edge_aggr<HEADS, HID><<<(ET + 1) / 2, 256, 0, stream>>>(
        ei0, ei1, asrc, adst, menc, bufA, bufB, ssum);
    k4_norm<HEADS, HID, true><<<(N_NODES * HC + 255) / 256, 256, 0, stream>>>(bufB, ssum, b1);

    // ---------------- Layer 2: bufB[N,128] -> bufB[N,128] (ELU) ----------------
    k1_gemm_alpha<HC, HC, HEADS><<<(N_NODES + 7) / 8, 256, 0, stream>>>(
        bufB, W2, aS2, aD2, bufA, asrc, adst, N_NODES);
    hipMemsetAsync(bufB, 0, (size_t)N_NODES * HC * sizeof(float), stream);
    hipMemsetAsync(menc, 0, (size_t)N_NODES * HEADS * sizeof(unsigned), stream);
    hipMemsetAsync(ssum, 0, (size_t)N_NODES * HEADS * sizeof(float), stream);
    k2_edge_max<HEADS><<<(ET + 255) / 256, 256, 0, stream>>>(ei0, ei1, asrc, adst, menc);
    k3_edge_aggr<HEADS, HID><<<(ET + 1) / 2, 256, 0, stream>>>(
        ei0, ei1, asrc, adst, menc, bufA, bufB, ssum);
    k4_norm<HEADS, HID, true><<<(N_NODES * HC + 255) / 256, 256, 0, stream>>>(bufB, ssum, b2);

    // ---------------- Layer 3: bufB[N,128] -> bufB[N,32] (no act, H=1) ----------------
    k1_gemm_alpha<HC, HID, 1><<<(N_NODES + 31) / 32, 256, 0, stream>>>(
        bufB, W3, aS3, aD3, bufA, asrc, adst, N_NODES);
    hipMemsetAsync(bufB, 0, (size_t)N_NODES * HID * sizeof(float), stream);
    hipMemsetAsync(menc, 0, (size_t)N_NODES * 1 * sizeof(unsigned), stream);
    hipMemsetAsync(ssum, 0, (size_t)N_NODES * 1 * sizeof(float), stream);
    k2_edge_max<1><<<(ET + 255) / 256, 256, 0, stream>>>(ei0, ei1, asrc, adst, menc);
    k3_edge_aggr<1, HID><<<(ET + 7) / 8, 256, 0, stream>>>(
        ei0, ei1, asrc, adst, menc, bufA, bufB, ssum);
    k4_norm<1, HID, false><<<(N_NODES * HID + 255) / 256, 256, 0, stream>>>(bufB, ssum, b3);

    // ---------------- Edge MLP on ORIGINAL edges ----------------
    k5_mlp<<<(E_EDGES + 255) / 256, 256, 0, stream>>>(
        ei0, ei1, bufB, ea, Wm1, bm1, Wm2, bm2, Wm3, bm3, out);
}

// Round 2
// 1640.087 us; speedup vs baseline: 1.5685x; 1.5685x over previous
//
#include <hip/hip_runtime.h>
#include <hip/hip_bf16.h>
#include <math.h>

#define N_NODES 50000
#define E_EDGES 800000
#define ET (E_EDGES + N_NODES)
#define NFEAT 16
#define EFEAT 8
#define HID 32
#define HEADS 4
#define HC 128

// ---- order-preserving float<->uint encoding for atomicMax on floats ----
__device__ __forceinline__ unsigned fenc(float f) {
    unsigned u = __float_as_uint(f);
    return (u & 0x80000000u) ? ~u : (u | 0x80000000u);
}
__device__ __forceinline__ float fdec(unsigned u) {
    return __uint_as_float((u & 0x80000000u) ? (u & 0x7FFFFFFFu) : ~u);
}
__device__ __forceinline__ float lrelu(float v) { return v > 0.f ? v : 0.2f * v; }

// ---- K1: h = x @ W ; alpha_src/dst = einsum(h, aS/aD) per head ----
template<int FIN, int HOUT, int H>
__global__ void k1_gemm_alpha(const float* __restrict__ x, const float* __restrict__ W,
                              const float* __restrict__ aS, const float* __restrict__ aD,
                              float* __restrict__ hout, float* __restrict__ asrc,
                              float* __restrict__ adst, int n_nodes)
{
    constexpr int GROUPS = 256 / HOUT;
    constexpr int NPT = 4;
    constexpr int NPB = GROUPS * NPT;
    __shared__ float xs[NPB * (FIN + 1)];
    const int tid = threadIdx.x;
    const int nb0 = blockIdx.x * NPB;
    for (int idx = tid; idx < NPB * FIN; idx += 256) {
        int node = idx / FIN, k = idx % FIN;
        int gn = nb0 + node;
        xs[node * (FIN + 1) + k] = (gn < n_nodes) ? x[gn * FIN + k] : 0.f;
    }
    __syncthreads();
    const int c = tid % HOUT;
    const int g = tid / HOUT;
    const int head = c / HID;
    const int cc = c % HID;
    const float aSv = aS[head * HID + cc];
    const float aDv = aD[head * HID + cc];
    float acc[NPT];
#pragma unroll
    for (int i = 0; i < NPT; i++) acc[i] = 0.f;
    for (int k = 0; k < FIN; k++) {
        float w = W[k * HOUT + c];
#pragma unroll
        for (int i = 0; i < NPT; i++)
            acc[i] += w * xs[(g * NPT + i) * (FIN + 1) + k];
    }
#pragma unroll
    for (int i = 0; i < NPT; i++) {
        int n = nb0 + g * NPT + i;
        bool ok = (n < n_nodes);
        float h = acc[i];
        if (ok) hout[n * HOUT + c] = h;
        float pa = h * aSv, pb = h * aDv;
#pragma unroll
        for (int off = 16; off >= 1; off >>= 1) {
            pa += __shfl_xor(pa, off, 32);
            pb += __shfl_xor(pb, off, 32);
        }
        if (ok && cc == 0) { asrc[n * H + head] = pa; adst[n * H + head] = pb; }
    }
}

// ---- K2: per-edge leaky_relu score, segment max into m[dst] (encoded) ----
template<int H>
__global__ void k2_edge_max(const int* __restrict__ ei0, const int* __restrict__ ei1,
                            const float* __restrict__ asrc, const float* __restrict__ adst,
                            unsigned* __restrict__ m)
{
    int e = blockIdx.x * blockDim.x + threadIdx.x;
    if (e >= ET) return;
    int s, d;
    if (e < E_EDGES) { s = ei0[e]; d = ei1[e]; } else { s = e - E_EDGES; d = s; }
#pragma unroll
    for (int h = 0; h < H; h++) {
        float v = lrelu(asrc[s * H + h] + adst[d * H + h]);
        atomicMax(&m[d * H + h], fenc(v));
    }
}

// ---- K3: ex = exp(e - m[dst]); acc[dst] += ex * h[src]; ssum[dst] += ex ----
template<int H, int C>
__global__ void k3_edge_aggr(const int* __restrict__ ei0, const int* __restrict__ ei1,
                             const float* __restrict__ asrc, const float* __restrict__ adst,
                             const unsigned* __restrict__ m, const float* __restrict__ hbuf,
                             float* __restrict__ acc, float* __restrict__ ssum)
{
    constexpr int TPE = H * C;
    constexpr int EPB = 256 / TPE;
    const int tid = threadIdx.x;
    int e = blockIdx.x * EPB + tid / TPE;
    if (e >= ET) return;
    const int t = tid % TPE;
    const int head = t / C;
    const int cc = t % C;
    int s, d;
    if (e < E_EDGES) { s = ei0[e]; d = ei1[e]; } else { s = e - E_EDGES; d = s; }
    float ev = lrelu(asrc[s * H + head] + adst[d * H + head]);
    float ex = __expf(ev - fdec(m[d * H + head]));
    float contrib = ex * hbuf[s * TPE + t];
    unsafeAtomicAdd(&acc[d * TPE + t], contrib);
    if (cc == 0) unsafeAtomicAdd(&ssum[d * H + head], ex);
}

// ---- K4: out = acc / (ssum + eps) + b ; optional ELU ; in place ----
template<int H, int C, bool DO_ELU>
__global__ void k4_norm(float* __restrict__ acc, const float* __restrict__ ssum,
                        const float* __restrict__ b)
{
    int idx = blockIdx.x * blockDim.x + threadIdx.x;
    if (idx >= N_NODES * H * C) return;
    int n = idx / (H * C);
    int t = idx % (H * C);
    int head = t / C;
    float v = acc[idx] / (ssum[n * H + head] + 1e-16f) + b[t];
    if (DO_ELU) v = v > 0.f ? v : __expf(v) - 1.f;
    acc[idx] = v;
}

// ---- K5: per-edge MLP 72 -> 32 -> 32 -> 1, softplus ----
// Restructured to keep only z1[32] live: stream inputs float4-at-a-time,
// FMA each component into all 32 accumulators. No big in[] array -> no spill.
__global__ __launch_bounds__(256) void k5_mlp(
                       const int* __restrict__ ei0, const int* __restrict__ ei1,
                       const float* __restrict__ h3, const float* __restrict__ ea,
                       const float* __restrict__ Wm1, const float* __restrict__ bm1,
                       const float* __restrict__ Wm2, const float* __restrict__ bm2,
                       const float* __restrict__ Wm3, const float* __restrict__ bm3,
                       float* __restrict__ out)
{
    __shared__ float w1[72 * 32], w2[32 * 32], w3s[32], b1s[32], b2s[32];
    __shared__ float b3s;
    const int tid = threadIdx.x;
    for (int i = tid; i < 72 * 32; i += 256) w1[i] = Wm1[i];
    for (int i = tid; i < 32 * 32; i += 256) w2[i] = Wm2[i];
    if (tid < 32) { w3s[tid] = Wm3[tid]; b1s[tid] = bm1[tid]; b2s[tid] = bm2[tid]; }
    if (tid == 0) b3s = bm3[0];
    __syncthreads();
    int e = blockIdx.x * 256 + tid;
    if (e >= E_EDGES) return;
    int s = ei0[e], d = ei1[e];

    float z1[32];
#pragma unroll
    for (int j = 0; j < 32; j++) z1[j] = b1s[j];

    const float4* hs = (const float4*)(h3 + (size_t)s * 32);
    const float4* hd = (const float4*)(h3 + (size_t)d * 32);
    const float4* eav = (const float4*)(ea + (size_t)e * 8);

#pragma unroll
    for (int kq = 0; kq < 8; kq++) {
        float4 v = hs[kq];
        const float* wrow = &w1[(kq * 4) * 32];
#pragma unroll
        for (int j = 0; j < 32; j++) z1[j] += v.x * wrow[0 * 32 + j];
#pragma unroll
        for (int j = 0; j < 32; j++) z1[j] += v.y * wrow[1 * 32 + j];
#pragma unroll
        for (int j = 0; j < 32; j++) z1[j] += v.z * wrow[2 * 32 + j];
#pragma unroll
        for (int j = 0; j < 32; j++) z1[j] += v.w * wrow[3 * 32 + j];
    }
#pragma unroll
    for (int kq = 0; kq < 8; kq++) {
        float4 v = hd[kq];
        const float* wrow = &w1[(32 + kq * 4) * 32];
#pragma unroll
        for (int j = 0; j < 32; j++) z1[j] += v.x * wrow[0 * 32 + j];
#pragma unroll
        for (int j = 0; j < 32; j++) z1[j] += v.y * wrow[1 * 32 + j];
#pragma unroll
        for (int j = 0; j < 32; j++) z1[j] += v.z * wrow[2 * 32 + j];
#pragma unroll
        for (int j = 0; j < 32; j++) z1[j] += v.w * wrow[3 * 32 + j];
    }
#pragma unroll
    for (int kq = 0; kq < 2; kq++) {
        float4 v = eav[kq];
        const float* wrow = &w1[(64 + kq * 4) * 32];
#pragma unroll
        for (int j = 0; j < 32; j++) z1[j] += v.x * wrow[0 * 32 + j];
#pragma unroll
        for (int j = 0; j < 32; j++) z1[j] += v.y * wrow[1 * 32 + j];
#pragma unroll
        for (int j = 0; j < 32; j++) z1[j] += v.z * wrow[2 * 32 + j];
#pragma unroll
        for (int j = 0; j < 32; j++) z1[j] += v.w * wrow[3 * 32 + j];
    }
    // ReLU on z1
#pragma unroll
    for (int j = 0; j < 32; j++) z1[j] = z1[j] > 0.f ? z1[j] : 0.f;

    float z3 = b3s;
#pragma unroll
    for (int j = 0; j < 32; j++) {
        float a = b2s[j];
#pragma unroll
        for (int k = 0; k < 32; k++) a += z1[k] * w2[k * 32 + j];
        z3 += (a > 0.f ? a : 0.f) * w3s[j];
    }
    out[e] = (z3 > 20.f) ? z3 : log1pf(__expf(z3));
}

extern "C" void kernel_launch(void* const* d_in, const int* in_sizes, int n_in,
                              void* d_out, int out_size, void* d_ws, size_t ws_size,
                              hipStream_t stream)
{
    const float* x   = (const float*)d_in[0];
    const int*   ei  = (const int*)d_in[1];
    const int*   ei0 = ei;
    const int*   ei1 = ei + E_EDGES;
    const float* ea  = (const float*)d_in[2];
    const float* W1  = (const float*)d_in[3];
    const float* aS1 = (const float*)d_in[4];
    const float* aD1 = (const float*)d_in[5];
    const float* b1  = (const float*)d_in[6];
    const float* W2  = (const float*)d_in[7];
    const float* aS2 = (const float*)d_in[8];
    const float* aD2 = (const float*)d_in[9];
    const float* b2  = (const float*)d_in[10];
    const float* W3  = (const float*)d_in[11];
    const float* aS3 = (const float*)d_in[12];
    const float* aD3 = (const float*)d_in[13];
    const float* b3  = (const float*)d_in[14];
    const float* Wm1 = (const float*)d_in[15];
    const float* bm1 = (const float*)d_in[16];
    const float* Wm2 = (const float*)d_in[17];
    const float* bm2 = (const float*)d_in[18];
    const float* Wm3 = (const float*)d_in[19];
    const float* bm3 = (const float*)d_in[20];

    float* ws = (float*)d_ws;
    float* bufA = ws;                                   // [N,128] h of current layer
    float* bufB = bufA + (size_t)N_NODES * HC;          // [N,128] acc / layer output
    float* asrc = bufB + (size_t)N_NODES * HC;          // [N,4]
    float* adst = asrc + (size_t)N_NODES * HEADS;       // [N,4]
    unsigned* menc = (unsigned*)(adst + (size_t)N_NODES * HEADS);  // [N,4]
    float* ssum = (float*)(menc + (size_t)N_NODES * HEADS);        // [N,4]

    float* out = (float*)d_out;

    // ---------------- Layer 1: x[N,16] -> bufB[N,128] (ELU) ----------------
    k1_gemm_alpha<NFEAT, HC, HEADS><<<(N_NODES + 7) / 8, 256, 0, stream>>>(
        x, W1, aS1, aD1, bufA, asrc, adst, N_NODES);
    hipMemsetAsync(bufB, 0, (size_t)N_NODES * HC * sizeof(float), stream);
    hipMemsetAsync(menc, 0, (size_t)N_NODES * HEADS * sizeof(unsigned), stream);
    hipMemsetAsync(ssum, 0, (size_t)N_NODES * HEADS * sizeof(float), stream);
    k2_edge_max<HEADS><<<(ET + 255) / 256, 256, 0, stream>>>(ei0, ei1, asrc, adst, menc);
    k3_edge_aggr<HEADS, HID><<<(ET + 1) / 2, 256, 0, stream>>>(
        ei0, ei1, asrc, adst, menc, bufA, bufB, ssum);
    k4_norm<HEADS, HID, true><<<(N_NODES * HC + 255) / 256, 256, 0, stream>>>(bufB, ssum, b1);

    // ---------------- Layer 2: bufB[N,128] -> bufB[N,128] (ELU) ----------------
    k1_gemm_alpha<HC, HC, HEADS><<<(N_NODES + 7) / 8, 256, 0, stream>>>(
        bufB, W2, aS2, aD2, bufA, asrc, adst, N_NODES);
    hipMemsetAsync(bufB, 0, (size_t)N_NODES * HC * sizeof(float), stream);
    hipMemsetAsync(menc, 0, (size_t)N_NODES * HEADS * sizeof(unsigned), stream);
    hipMemsetAsync(ssum, 0, (size_t)N_NODES * HEADS * sizeof(float), stream);
    k2_edge_max<HEADS><<<(ET + 255) / 256, 256, 0, stream>>>(ei0, ei1, asrc, adst, menc);
    k3_edge_aggr<HEADS, HID><<<(ET + 1) / 2, 256, 0, stream>>>(
        ei0, ei1, asrc, adst, menc, bufA, bufB, ssum);
    k4_norm<HEADS, HID, true><<<(N_NODES * HC + 255) / 256, 256, 0, stream>>>(bufB, ssum, b2);

    // ---------------- Layer 3: bufB[N,128] -> bufB[N,32] (no act, H=1) ----------------
    k1_gemm_alpha<HC, HID, 1><<<(N_NODES + 31) / 32, 256, 0, stream>>>(
        bufB, W3, aS3, aD3, bufA, asrc, adst, N_NODES);
    hipMemsetAsync(bufB, 0, (size_t)N_NODES * HID * sizeof(float), stream);
    hipMemsetAsync(menc, 0, (size_t)N_NODES * 1 * sizeof(unsigned), stream);
    hipMemsetAsync(ssum, 0, (size_t)N_NODES * 1 * sizeof(float), stream);
    k2_edge_max<1><<<(ET + 255) / 256, 256, 0, stream>>>(ei0, ei1, asrc, adst, menc);
    k3_edge_aggr<1, HID><<<(ET + 7) / 8, 256, 0, stream>>>(
        ei0, ei1, asrc, adst, menc, bufA, bufB, ssum);
    k4_norm<1, HID, false><<<(N_NODES * HID + 255) / 256, 256, 0, stream>>>(bufB, ssum, b3);

    // ---------------- Edge MLP on ORIGINAL edges ----------------
    k5_mlp<<<(E_EDGES + 255) / 256, 256, 0, stream>>>(
        ei0, ei1, bufB, ea, Wm1, bm1, Wm2, bm2, Wm3, bm3, out);
}

// Round 3
// 681.924 us; speedup vs baseline: 3.7724x; 2.4051x over previous
//
#include <hip/hip_runtime.h>
#include <hip/hip_bf16.h>
#include <math.h>

#define N_NODES 50000
#define E_EDGES 800000
#define NFEAT 16
#define EFEAT 8
#define HID 32
#define HEADS 4
#define HC 128

__device__ __forceinline__ float lrelu(float v) { return v > 0.f ? v : 0.2f * v; }

// ---- K1: h = x @ W ; alpha_src/dst = einsum(h, aS/aD) per head ----
template<int FIN, int HOUT, int H>
__global__ void k1_gemm_alpha(const float* __restrict__ x, const float* __restrict__ W,
                              const float* __restrict__ aS, const float* __restrict__ aD,
                              float* __restrict__ hout, float* __restrict__ asrc,
                              float* __restrict__ adst, int n_nodes)
{
    constexpr int GROUPS = 256 / HOUT;
    constexpr int NPT = 4;
    constexpr int NPB = GROUPS * NPT;
    __shared__ float xs[NPB * (FIN + 1)];
    const int tid = threadIdx.x;
    const int nb0 = blockIdx.x * NPB;
    for (int idx = tid; idx < NPB * FIN; idx += 256) {
        int node = idx / FIN, k = idx % FIN;
        int gn = nb0 + node;
        xs[node * (FIN + 1) + k] = (gn < n_nodes) ? x[gn * FIN + k] : 0.f;
    }
    __syncthreads();
    const int c = tid % HOUT;
    const int g = tid / HOUT;
    const int head = c / HID;
    const int cc = c % HID;
    const float aSv = aS[head * HID + cc];
    const float aDv = aD[head * HID + cc];
    float acc[NPT];
#pragma unroll
    for (int i = 0; i < NPT; i++) acc[i] = 0.f;
    for (int k = 0; k < FIN; k++) {
        float w = W[k * HOUT + c];
#pragma unroll
        for (int i = 0; i < NPT; i++)
            acc[i] += w * xs[(g * NPT + i) * (FIN + 1) + k];
    }
#pragma unroll
    for (int i = 0; i < NPT; i++) {
        int n = nb0 + g * NPT + i;
        bool ok = (n < n_nodes);
        float h = acc[i];
        if (ok) hout[n * HOUT + c] = h;
        float pa = h * aSv, pb = h * aDv;
#pragma unroll
        for (int off = 16; off >= 1; off >>= 1) {
            pa += __shfl_xor(pa, off, 32);
            pb += __shfl_xor(pb, off, 32);
        }
        if (ok && cc == 0) { asrc[n * H + head] = pa; adst[n * H + head] = pb; }
    }
}

// ---- CSR build: histogram -> single-block scan -> scatter ----
__global__ void kc_count(const int* __restrict__ ei1, int* __restrict__ cnt)
{
    int e = blockIdx.x * 256 + threadIdx.x;
    if (e >= E_EDGES) return;
    atomicAdd(&cnt[ei1[e]], 1);
}

__global__ __launch_bounds__(1024) void kc_scan(const int* __restrict__ cnt,
                                                int* __restrict__ rowptr,
                                                int* __restrict__ cur)
{
    __shared__ int tsum[1024];
    const int t = threadIdx.x;
    const int CH = (N_NODES + 1023) / 1024;  // 49
    int lo = t * CH, hi = lo + CH;
    if (hi > N_NODES) hi = N_NODES;
    int s = 0;
    for (int i = lo; i < hi; i++) s += cnt[i];
    tsum[t] = s;
    __syncthreads();
    for (int off = 1; off < 1024; off <<= 1) {
        int v = (t >= off) ? tsum[t - off] : 0;
        __syncthreads();
        tsum[t] += v;
        __syncthreads();
    }
    int run = (t == 0) ? 0 : tsum[t - 1];
    for (int i = lo; i < hi; i++) {
        rowptr[i] = run;
        cur[i] = run;
        run += cnt[i];
    }
}

__global__ void kc_scatter(const int* __restrict__ ei0, const int* __restrict__ ei1,
                           int* __restrict__ cur, int* __restrict__ srcs)
{
    int e = blockIdx.x * 256 + threadIdx.x;
    if (e >= E_EDGES) return;
    int pos = atomicAdd(&cur[ei1[e]], 1);
    srcs[pos] = ei0[e];
}

// ---- fused aggregation: online segment-softmax + weighted sum + bias (+ELU) ----
// TPE = H*C/2 threads per node; each thread owns 2 channels (float2).
// Self-loop is the init state. No atomics, no extra passes.
template<int H, int C, bool DO_ELU>
__global__ __launch_bounds__(256) void k_aggr(
    const float* __restrict__ asrc, const float* __restrict__ adst,
    const float* __restrict__ hbuf, const int* __restrict__ rowptr,
    const int* __restrict__ deg, const int* __restrict__ srcs,
    const float* __restrict__ b, float* __restrict__ outp)
{
    constexpr int HCL = H * C;
    constexpr int TPE = HCL / 2;
    constexpr int NPB = 256 / TPE;
    const int t = threadIdx.x % TPE;
    const int n = blockIdx.x * NPB + threadIdx.x / TPE;
    if (n >= N_NODES) return;
    const int c0 = 2 * t;
    const int head = c0 / C;
    const float adstv = adst[n * H + head];
    // init with self-loop
    float m = lrelu(asrc[n * H + head] + adstv);
    float ssum = 1.f;
    float2 hv = *(const float2*)(hbuf + (size_t)n * HCL + c0);
    float a0 = hv.x, a1 = hv.y;
    const int base = rowptr[n];
    const int dg = deg[n];
    for (int i = 0; i < dg; i++) {
        int s = srcs[base + i];
        float sc = lrelu(asrc[s * H + head] + adstv);
        float2 hs = *(const float2*)(hbuf + (size_t)s * HCL + c0);
        float ex;
        if (sc > m) {
            float r = __expf(m - sc);
            ssum *= r; a0 *= r; a1 *= r;
            m = sc;
            ex = 1.f;
        } else {
            ex = __expf(sc - m);
        }
        ssum += ex;
        a0 += ex * hs.x;
        a1 += ex * hs.y;
    }
    float inv = 1.f / (ssum + 1e-16f);
    float v0 = a0 * inv + b[c0];
    float v1 = a1 * inv + b[c0 + 1];
    if (DO_ELU) {
        v0 = v0 > 0.f ? v0 : __expf(v0) - 1.f;
        v1 = v1 > 0.f ? v1 : __expf(v1) - 1.f;
    }
    *(float2*)(outp + (size_t)n * HCL + c0) = make_float2(v0, v1);
}

// ---- K5: per-edge MLP 72 -> 32 -> 32 -> 1, softplus (spill-free streaming) ----
__global__ __launch_bounds__(256) void k5_mlp(
                       const int* __restrict__ ei0, const int* __restrict__ ei1,
                       const float* __restrict__ h3, const float* __restrict__ ea,
                       const float* __restrict__ Wm1, const float* __restrict__ bm1,
                       const float* __restrict__ Wm2, const float* __restrict__ bm2,
                       const float* __restrict__ Wm3, const float* __restrict__ bm3,
                       float* __restrict__ out)
{
    __shared__ float w1[72 * 32], w2[32 * 32], w3s[32], b1s[32], b2s[32];
    __shared__ float b3s;
    const int tid = threadIdx.x;
    for (int i = tid; i < 72 * 32; i += 256) w1[i] = Wm1[i];
    for (int i = tid; i < 32 * 32; i += 256) w2[i] = Wm2[i];
    if (tid < 32) { w3s[tid] = Wm3[tid]; b1s[tid] = bm1[tid]; b2s[tid] = bm2[tid]; }
    if (tid == 0) b3s = bm3[0];
    __syncthreads();
    int e = blockIdx.x * 256 + tid;
    if (e >= E_EDGES) return;
    int s = ei0[e], d = ei1[e];

    float z1[32];
#pragma unroll
    for (int j = 0; j < 32; j++) z1[j] = b1s[j];

    const float4* hs = (const float4*)(h3 + (size_t)s * 32);
    const float4* hd = (const float4*)(h3 + (size_t)d * 32);
    const float4* eav = (const float4*)(ea + (size_t)e * 8);

#pragma unroll
    for (int kq = 0; kq < 8; kq++) {
        float4 v = hs[kq];
        const float* wrow = &w1[(kq * 4) * 32];
#pragma unroll
        for (int j = 0; j < 32; j++) z1[j] += v.x * wrow[0 * 32 + j];
#pragma unroll
        for (int j = 0; j < 32; j++) z1[j] += v.y * wrow[1 * 32 + j];
#pragma unroll
        for (int j = 0; j < 32; j++) z1[j] += v.z * wrow[2 * 32 + j];
#pragma unroll
        for (int j = 0; j < 32; j++) z1[j] += v.w * wrow[3 * 32 + j];
    }
#pragma unroll
    for (int kq = 0; kq < 8; kq++) {
        float4 v = hd[kq];
        const float* wrow = &w1[(32 + kq * 4) * 32];
#pragma unroll
        for (int j = 0; j < 32; j++) z1[j] += v.x * wrow[0 * 32 + j];
#pragma unroll
        for (int j = 0; j < 32; j++) z1[j] += v.y * wrow[1 * 32 + j];
#pragma unroll
        for (int j = 0; j < 32; j++) z1[j] += v.z * wrow[2 * 32 + j];
#pragma unroll
        for (int j = 0; j < 32; j++) z1[j] += v.w * wrow[3 * 32 + j];
    }
#pragma unroll
    for (int kq = 0; kq < 2; kq++) {
        float4 v = eav[kq];
        const float* wrow = &w1[(64 + kq * 4) * 32];
#pragma unroll
        for (int j = 0; j < 32; j++) z1[j] += v.x * wrow[0 * 32 + j];
#pragma unroll
        for (int j = 0; j < 32; j++) z1[j] += v.y * wrow[1 * 32 + j];
#pragma unroll
        for (int j = 0; j < 32; j++) z1[j] += v.z * wrow[2 * 32 + j];
#pragma unroll
        for (int j = 0; j < 32; j++) z1[j] += v.w * wrow[3 * 32 + j];
    }
#pragma unroll
    for (int j = 0; j < 32; j++) z1[j] = z1[j] > 0.f ? z1[j] : 0.f;

    float z3 = b3s;
#pragma unroll
    for (int j = 0; j < 32; j++) {
        float a = b2s[j];
#pragma unroll
        for (int k = 0; k < 32; k++) a += z1[k] * w2[k * 32 + j];
        z3 += (a > 0.f ? a : 0.f) * w3s[j];
    }
    out[e] = (z3 > 20.f) ? z3 : log1pf(__expf(z3));
}

extern "C" void kernel_launch(void* const* d_in, const int* in_sizes, int n_in,
                              void* d_out, int out_size, void* d_ws, size_t ws_size,
                              hipStream_t stream)
{
    const float* x   = (const float*)d_in[0];
    const int*   ei  = (const int*)d_in[1];
    const int*   ei0 = ei;
    const int*   ei1 = ei + E_EDGES;
    const float* ea  = (const float*)d_in[2];
    const float* W1  = (const float*)d_in[3];
    const float* aS1 = (const float*)d_in[4];
    const float* aD1 = (const float*)d_in[5];
    const float* b1  = (const float*)d_in[6];
    const float* W2  = (const float*)d_in[7];
    const float* aS2 = (const float*)d_in[8];
    const float* aD2 = (const float*)d_in[9];
    const float* b2  = (const float*)d_in[10];
    const float* W3  = (const float*)d_in[11];
    const float* aS3 = (const float*)d_in[12];
    const float* aD3 = (const float*)d_in[13];
    const float* b3  = (const float*)d_in[14];
    const float* Wm1 = (const float*)d_in[15];
    const float* bm1 = (const float*)d_in[16];
    const float* Wm2 = (const float*)d_in[17];
    const float* bm2 = (const float*)d_in[18];
    const float* Wm3 = (const float*)d_in[19];
    const float* bm3 = (const float*)d_in[20];

    float* ws = (float*)d_ws;
    float* bufA = ws;                                    // [N,128] h of current layer
    float* bufB = bufA + (size_t)N_NODES * HC;           // [N,128] layer output
    float* asrc = bufB + (size_t)N_NODES * HC;           // [N,4]
    float* adst = asrc + (size_t)N_NODES * HEADS;        // [N,4]
    int* cnt    = (int*)(adst + (size_t)N_NODES * HEADS);// [N] in-degree (no self-loop)
    int* rowptr = cnt + N_NODES;                         // [N]
    int* cur    = rowptr + N_NODES;                      // [N]
    int* srcs   = cur + N_NODES;                         // [E]

    float* out = (float*)d_out;

    // ---------------- CSR build (once; shared by all 3 layers) ----------------
    hipMemsetAsync(cnt, 0, (size_t)N_NODES * sizeof(int), stream);
    kc_count<<<(E_EDGES + 255) / 256, 256, 0, stream>>>(ei1, cnt);
    kc_scan<<<1, 1024, 0, stream>>>(cnt, rowptr, cur);
    kc_scatter<<<(E_EDGES + 255) / 256, 256, 0, stream>>>(ei0, ei1, cur, srcs);

    // ---------------- Layer 1: x[N,16] -> bufB[N,128] (ELU) ----------------
    k1_gemm_alpha<NFEAT, HC, HEADS><<<(N_NODES + 7) / 8, 256, 0, stream>>>(
        x, W1, aS1, aD1, bufA, asrc, adst, N_NODES);
    k_aggr<HEADS, HID, true><<<(N_NODES + 3) / 4, 256, 0, stream>>>(
        asrc, adst, bufA, rowptr, cnt, srcs, b1, bufB);

    // ---------------- Layer 2: bufB[N,128] -> bufB[N,128] (ELU) ----------------
    k1_gemm_alpha<HC, HC, HEADS><<<(N_NODES + 7) / 8, 256, 0, stream>>>(
        bufB, W2, aS2, aD2, bufA, asrc, adst, N_NODES);
    k_aggr<HEADS, HID, true><<<(N_NODES + 3) / 4, 256, 0, stream>>>(
        asrc, adst, bufA, rowptr, cnt, srcs, b2, bufB);

    // ---------------- Layer 3: bufB[N,128] -> bufB[N,32] (no act, H=1) ----------------
    k1_gemm_alpha<HC, HID, 1><<<(N_NODES + 31) / 32, 256, 0, stream>>>(
        bufB, W3, aS3, aD3, bufA, asrc, adst, N_NODES);
    k_aggr<1, HID, false><<<(N_NODES + 15) / 16, 256, 0, stream>>>(
        asrc, adst, bufA, rowptr, cnt, srcs, b3, bufB);

    // ---------------- Edge MLP on ORIGINAL edges ----------------
    k5_mlp<<<(E_EDGES + 255) / 256, 256, 0, stream>>>(
        ei0, ei1, bufB, ea, Wm1, bm1, Wm2, bm2, Wm3, bm3, out);
}